// Round 13
// baseline (140.392 us; speedup 1.0000x reference)
//
#include <hip/hip_runtime.h>
#include <hip/hip_bf16.h>
#include <stdint.h>

// Problem constants
#define B_  8
#define S_  1024
#define H_  1024
#define NH_ 16
#define HD_ 64
#define M_  (B_*S_)   // 8192 rows of hidden

using bf16x8 = __attribute__((ext_vector_type(8))) __bf16;
using f32x4  = __attribute__((ext_vector_type(4))) float;
using f32x16 = __attribute__((ext_vector_type(16))) float;
typedef int iv2 __attribute__((ext_vector_type(2)));

#define LOG2E 1.4426950408889634f

#if __has_builtin(__builtin_amdgcn_exp2f)
#define EXP2(x) __builtin_amdgcn_exp2f(x)
#else
#define EXP2(x) exp2f(x)
#endif

#define SBAR() asm volatile("s_barrier" ::: "memory")
#define WAITV(n) asm volatile("s_waitcnt vmcnt(" #n ")" ::: "memory")

// async global->LDS, 16B per lane; lds ptr must be wave-uniform (HW adds lane*16)
__device__ __forceinline__ void gload_lds16(const void* g, void* l) {
  __builtin_amdgcn_global_load_lds(
      (const __attribute__((address_space(1))) unsigned int*)g,
      (__attribute__((address_space(3))) unsigned int*)l, 16, 0, 0);
}

// pack two f32 -> one u32 of 2 bf16 (lo in bits 0-15)
__device__ __forceinline__ unsigned pack_bf16(float lo, float hi) {
  unsigned r;
  asm("v_cvt_pk_bf16_f32 %0, %1, %2" : "=v"(r) : "v"(lo), "v"(hi));
  return r;
}

// swap a.hi32lanes <-> b.lo32lanes
__device__ __forceinline__ void swapl32(unsigned& a, unsigned& b) {
#if __has_builtin(__builtin_amdgcn_permlane32_swap)
  iv2 r = __builtin_amdgcn_permlane32_swap((int)a, (int)b, false, false);
  a = (unsigned)r[0];
  b = (unsigned)r[1];
#else
  unsigned axc = (unsigned)__shfl_xor((int)a, 32);
  unsigned bxc = (unsigned)__shfl_xor((int)b, 32);
  int lane = threadIdx.x & 63;
  unsigned an = (lane < 32) ? a : bxc;
  unsigned bn = (lane < 32) ? axc : b;
  a = an; b = bn;
#endif
}

// ---------------------------------------------------------------------------
// fp32 -> bf16 cast, single fused launch: dst is the contiguous Xb|Wq|Wk|Wv
// bf16 region (1,441,792 vec8-chunks); source switches per chunk index.
// ---------------------------------------------------------------------------
#define XCHUNKS 1048576   // M_*H_/8
#define WCHUNKS 131072    // H_*H_/8

__global__ void __launch_bounds__(256) cast_all_bf16_kernel(
    const float* __restrict__ hs,
    const float* __restrict__ w0, const float* __restrict__ w1,
    const float* __restrict__ w2, __bf16* __restrict__ dst) {
  int i = blockIdx.x * blockDim.x + threadIdx.x;  // [0, 1441792)
  const float* s;
  int rem;
  if (i < XCHUNKS) {
    s = hs; rem = i;
  } else {
    int j = i - XCHUNKS;
    int seg = j >> 17;
    rem = j & (WCHUNKS - 1);
    s = (seg == 0) ? w0 : ((seg == 1) ? w1 : w2);
  }
  float4 f0 = ((const float4*)s)[2 * rem];
  float4 f1 = ((const float4*)s)[2 * rem + 1];
  bf16x8 o;
  o[0] = (__bf16)f0.x; o[1] = (__bf16)f0.y; o[2] = (__bf16)f0.z; o[3] = (__bf16)f0.w;
  o[4] = (__bf16)f1.x; o[5] = (__bf16)f1.y; o[6] = (__bf16)f1.z; o[7] = (__bf16)f1.w;
  ((bf16x8*)dst)[i] = o;
}

// ---------------------------------------------------------------------------
// QKV projection GEMM (r8 loop/tile/staging + 32x32x16 MFMA, new this round):
//   C = X @ W^T + b; BM=256, BN=128, BK=64; 8 waves (4m x 2n), wave 64x64.
//   Wave tile via 2x2 of 32x32x16 (vs 4x4 of 16x16x32): half the MFMA count,
//   same ds_read count, ~15% higher matrix-pipe ceiling (m119).
//   A/B frag + C/D layouts identical to the session-verified attn usage:
//   A row = lane&31, k-chunk = 2ks+hi; D col = lane&31, row = CROW(r,hi).
//   Grid (32, 8, 3) = 768 blocks = 3 blocks/CU; LDS 48 KB single-buffered.
// Outputs: z=0 -> Q [B,NH,S,HD] * (0.125*log2e) ; z=1 -> K ; z=2 -> V^T
// ---------------------------------------------------------------------------
#define CROW(r, hi) (((r) & 3) + 8 * ((r) >> 2) + 4 * (hi))

__global__ void __launch_bounds__(512) qkv_gemm_kernel(
    const __bf16* __restrict__ X,
    const __bf16* __restrict__ Wq, const __bf16* __restrict__ Wk, const __bf16* __restrict__ Wv,
    const float* __restrict__ bq, const float* __restrict__ bk, const float* __restrict__ bv,
    __bf16* __restrict__ Qo, __bf16* __restrict__ Ko, __bf16* __restrict__ Vto) {
  __shared__ __align__(16) char Asm[256 * 128];  // [256 rows][64 k] bf16, swizzled
  __shared__ __align__(16) char Bsm[128 * 128];  // [128 rows][64 k] bf16, swizzled

  const int tid = threadIdx.x;
  const int lane = tid & 63, w = tid >> 6;
  const int l31 = lane & 31, hi = lane >> 5;
  const int wm = w >> 1, wn = w & 1;          // 4m x 2n waves
  const int m0 = blockIdx.x * 256;
  const int n0 = blockIdx.y * 128;
  const int z = blockIdx.z;
  const __bf16* W = (z == 0) ? Wq : ((z == 1) ? Wk : Wv);
  const float* bias = (z == 0) ? bq : ((z == 1) ? bk : bv);

  f32x16 acc[2][2] = {};   // [mi][nj] 32x32 fragments

  for (int kt = 0; kt < H_; kt += 64) {
    __syncthreads();
    // stage A[256][64] (4 rounds) and B[128][64] (2 rounds); pre-swizzled src
#pragma unroll
    for (int is = 0; is < 4; ++is) {
      int q = is * 8192 + tid * 16;            // linear LDS byte this lane fills
      int row = q >> 7;                        // 128B rows
      int inrow = (q & 127) ^ ((row & 7) << 4);
      const char* ga = (const char*)X + (size_t)(m0 + row) * (H_ * 2) + kt * 2 + inrow;
      gload_lds16(ga, Asm + is * 8192 + w * 1024);
    }
#pragma unroll
    for (int is = 0; is < 2; ++is) {
      int q = is * 8192 + tid * 16;
      int row = q >> 7;                        // 0..127
      int inrow = (q & 127) ^ ((row & 7) << 4);
      const char* gb = (const char*)W + (size_t)(n0 + row) * (H_ * 2) + kt * 2 + inrow;
      gload_lds16(gb, Bsm + is * 8192 + w * 1024);
    }
    __syncthreads();
#pragma unroll
    for (int ks = 0; ks < 4; ++ks) {           // K=16 per MFMA, 4 steps
      bf16x8 a[2], b[2];
#pragma unroll
      for (int mi = 0; mi < 2; ++mi) {
        int row = wm * 64 + mi * 32 + l31;
        int chunk = (2 * ks + hi) ^ (row & 7);
        a[mi] = *reinterpret_cast<const bf16x8*>(Asm + row * 128 + chunk * 16);
      }
#pragma unroll
      for (int nj = 0; nj < 2; ++nj) {
        int row = wn * 64 + nj * 32 + l31;
        int chunk = (2 * ks + hi) ^ (row & 7);
        b[nj] = *reinterpret_cast<const bf16x8*>(Bsm + row * 128 + chunk * 16);
      }
#pragma unroll
      for (int mi = 0; mi < 2; ++mi)
#pragma unroll
        for (int nj = 0; nj < 2; ++nj)
          acc[mi][nj] = __builtin_amdgcn_mfma_f32_32x32x16_bf16(a[mi], b[nj], acc[mi][nj], 0, 0, 0);
    }
  }

  // epilogue: 32x32 C/D frag col=l31, row=CROW(r,hi) (verified mapping)
#pragma unroll
  for (int nj = 0; nj < 2; ++nj) {
    const int n = n0 + wn * 64 + nj * 32 + l31;
    const float bs = bias[n];
    const int nh = n >> 6, d = n & 63;
#pragma unroll
    for (int mi = 0; mi < 2; ++mi) {
#pragma unroll
      for (int r = 0; r < 16; ++r) {
        const int m = m0 + wm * 64 + mi * 32 + CROW(r, hi);
        const int bb = m >> 10, s = m & 1023;
        const float v = acc[mi][nj][r] + bs;
        if (z == 0) {
          Qo[(((size_t)bb * NH_ + nh) * S_ + s) * HD_ + d] = (__bf16)(v * (0.125f * LOG2E));
        } else if (z == 1) {
          Ko[(((size_t)bb * NH_ + nh) * S_ + s) * HD_ + d] = (__bf16)v;
        } else {
          Vto[(((size_t)bb * NH_ + nh) * HD_ + d) * S_ + s] = (__bf16)v;
        }
      }
    }
  }
}

// ---------------------------------------------------------------------------
// Flash attention, 8-wave 32x32 + K/V double-buffer + defer-max (r12 exact)
// ---------------------------------------------------------------------------
__global__ void __launch_bounds__(512) attn_kernel(
    const __bf16* __restrict__ Q,   // [128][1024][64]
    const __bf16* __restrict__ K,   // [128][1024][64]
    const __bf16* __restrict__ Vt,  // [128][64][1024]
    float* __restrict__ Out) {      // [8][1024][1024]
  __shared__ __align__(16) char Ksm[2][8192];
  __shared__ __align__(16) char Vsm[2][8192];
  __shared__ __align__(16) float stat_lds[512];

  const int tid = threadIdx.x, lane = tid & 63, w = tid >> 6;
  const int l31 = lane & 31, hi = lane >> 5;
  const int head = blockIdx.y;
  const int bb = head >> 4, nh = head & 15;
  const int qw = blockIdx.x * 256 + w * 32;

  const char* Qh = (const char*)(Q + (size_t)head * S_ * HD_);
  const char* Kh = (const char*)(K + (size_t)head * S_ * HD_);
  const char* Vh = (const char*)(Vt + (size_t)head * S_ * HD_);

  const int srow = (tid * 16) >> 7;
  const int sinrow = ((tid * 16) & 127) ^ ((srow & 7) << 4);

  bf16x8 qf[4];
#pragma unroll
  for (int slot = 0; slot < 4; ++slot)
    qf[slot] = *reinterpret_cast<const bf16x8*>(
        Qh + (size_t)(qw + l31) * 128 + slot * 32 + hi * 16);

  float m_run = -1e30f, l_run = 0.0f;
  f32x16 accO[2] = {};

  gload_lds16(Kh + (size_t)srow * 128 + sinrow, Ksm[0] + w * 1024);
  gload_lds16(Vh + (size_t)srow * 2048 + sinrow, Vsm[0] + w * 1024);

  for (int t = 0; t < 16; ++t) {
    const int cur = t & 1;
    if (t < 15) {
      const int nxt = cur ^ 1;
      const size_t kvn = (size_t)(t + 1) * 64;
      gload_lds16(Kh + (size_t)(kvn + srow) * 128 + sinrow, Ksm[nxt] + w * 1024);
      gload_lds16(Vh + (size_t)srow * 2048 + kvn * 2 + sinrow, Vsm[nxt] + w * 1024);
      WAITV(2);
    } else {
      WAITV(0);
    }
    SBAR();

    const char* Kc = Ksm[cur];
    const char* Vc = Vsm[cur];

    f32x16 s0 = {}, s1 = {};
    __builtin_amdgcn_s_setprio(1);
#pragma unroll
    for (int slot = 0; slot < 4; ++slot) {
      int c0 = slot * 2 + hi;
      int r0 = l31;
      bf16x8 k0 = *reinterpret_cast<const bf16x8*>(Kc + r0 * 128 + ((c0 ^ (r0 & 7)) << 4));
      int r1 = 32 + l31;
      bf16x8 k1 = *reinterpret_cast<const bf16x8*>(Kc + r1 * 128 + ((c0 ^ (r1 & 7)) << 4));
      s0 = __builtin_amdgcn_mfma_f32_32x32x16_bf16(k0, qf[slot], s0, 0, 0, 0);
      s1 = __builtin_amdgcn_mfma_f32_32x32x16_bf16(k1, qf[slot], s1, 0, 0, 0);
    }
    __builtin_amdgcn_s_setprio(0);

    // ---- online softmax with defer-max (exp2 domain)
    float mx = -1e30f;
#pragma unroll
    for (int r = 0; r < 16; ++r) mx = fmaxf(mx, fmaxf(s0[r], s1[r]));
    mx = fmaxf(mx, __shfl_xor(mx, 32));

    float corr = 1.0f;
    if (!__all(mx - m_run <= 8.0f)) {
      float mnew = fmaxf(m_run, mx);
      corr = EXP2(m_run - mnew);
      m_run = mnew;
      stat_lds[w * 64 + lane] = corr;
      f32x4 c4[4];
#pragma unroll
      for (int rq = 0; rq < 4; ++rq)
        c4[rq] = *reinterpret_cast<const f32x4*>(&stat_lds[w * 64 + rq * 8 + hi * 4]);
#pragma unroll
      for (int r = 0; r < 16; ++r) {
        float cr = c4[r >> 2][r & 3];
        accO[0][r] *= cr;
        accO[1][r] *= cr;
      }
    }

    float sum = 0.0f;
#pragma unroll
    for (int r = 0; r < 16; ++r) {
      float p0 = EXP2(s0[r] - m_run); s0[r] = p0; sum += p0;
      float p1 = EXP2(s1[r] - m_run); s1[r] = p1; sum += p1;
    }
    sum += __shfl_xor(sum, 32);
    l_run = l_run * corr + sum;

    bf16x8 pa[4];
#define BUILD_PA(T, rb)                                                     \
    {                                                                       \
      unsigned x1 = pack_bf16(T[rb + 0], T[rb + 1]);                        \
      unsigned x2 = pack_bf16(T[rb + 2], T[rb + 3]);                        \
      unsigned y1 = pack_bf16(T[rb + 4], T[rb + 5]);                        \
      unsigned y2 = pack_bf16(T[rb + 6], T[rb + 7]);                        \
      swapl32(x1, y1);                                                      \
      swapl32(x2, y2);                                                      \
      union { unsigned u[4]; bf16x8 v; } cvt;                               \
      cvt.u[0] = x1; cvt.u[1] = x2; cvt.u[2] = y1; cvt.u[3] = y2;           \
      pa_out = cvt.v;                                                       \
    }
    {
      bf16x8 pa_out;
      BUILD_PA(s0, 0) pa[0] = pa_out;
      BUILD_PA(s0, 8) pa[1] = pa_out;
      BUILD_PA(s1, 0) pa[2] = pa_out;
      BUILD_PA(s1, 8) pa[3] = pa_out;
    }

    __builtin_amdgcn_s_setprio(1);
#pragma unroll
    for (int ks = 0; ks < 4; ++ks) {
#pragma unroll
      for (int dt = 0; dt < 2; ++dt) {
        int rd = dt * 32 + l31;
        int ck = ks * 2 + hi;
        bf16x8 vb = *reinterpret_cast<const bf16x8*>(Vc + rd * 128 + ((ck ^ (rd & 7)) << 4));
        accO[dt] = __builtin_amdgcn_mfma_f32_32x32x16_bf16(pa[ks], vb, accO[dt], 0, 0, 0);
      }
    }
    __builtin_amdgcn_s_setprio(0);

    SBAR();
  }

  stat_lds[w * 64 + lane] = 1.0f / l_run;
  f32x4 li4[4];
#pragma unroll
  for (int rq = 0; rq < 4; ++rq)
    li4[rq] = *reinterpret_cast<const f32x4*>(&stat_lds[w * 64 + rq * 8 + hi * 4]);

  float* Ob = Out + (size_t)bb * S_ * H_ + (size_t)nh * HD_;
#pragma unroll
  for (int r = 0; r < 16; ++r) {
    int qabs = qw + CROW(r, hi);
    float li = li4[r >> 2][r & 3];
#pragma unroll
    for (int dt = 0; dt < 2; ++dt) {
      int d = dt * 32 + l31;
      Ob[(size_t)qabs * H_ + d] = accO[dt][r] * li;
    }
  }
}

// ---------------------------------------------------------------------------
extern "C" void kernel_launch(void* const* d_in, const int* in_sizes, int n_in,
                              void* d_out, int out_size, void* d_ws, size_t ws_size,
                              hipStream_t stream) {
  const float* hs = (const float*)d_in[0];
  const float* Wq = (const float*)d_in[1];
  const float* bq = (const float*)d_in[2];
  const float* Wk = (const float*)d_in[3];
  const float* bk = (const float*)d_in[4];
  const float* Wv = (const float*)d_in[5];
  const float* bv = (const float*)d_in[6];
  float* out = (float*)d_out;
  char* ws = (char*)d_ws;

  size_t off = 0;
  __bf16* Xb  = (__bf16*)(ws + off); off += (size_t)M_ * H_ * 2;
  __bf16* Wqb = (__bf16*)(ws + off); off += (size_t)H_ * H_ * 2;
  __bf16* Wkb = (__bf16*)(ws + off); off += (size_t)H_ * H_ * 2;
  __bf16* Wvb = (__bf16*)(ws + off); off += (size_t)H_ * H_ * 2;
  __bf16* Qb  = (__bf16*)(ws + off); off += (size_t)M_ * H_ * 2;
  __bf16* Kb  = (__bf16*)(ws + off); off += (size_t)M_ * H_ * 2;
  __bf16* Vtb = (__bf16*)(ws + off); off += (size_t)M_ * H_ * 2;

  // one cast launch covering Xb|Wqb|Wkb|Wvb (contiguous dst)
  cast_all_bf16_kernel<<<(XCHUNKS + 3 * WCHUNKS) / 256, 256, 0, stream>>>(
      hs, Wq, Wk, Wv, Xb);

  qkv_gemm_kernel<<<dim3(M_ / 256, H_ / 128, 3), 512, 0, stream>>>(
      Xb, Wqb, Wkb, Wvb, bq, bk, bv, Qb, Kb, Vtb);

  attn_kernel<<<dim3(S_ / 256, B_ * NH_), 512, 0, stream>>>(Qb, Kb, Vtb, out);
}

// Round 14
// 133.959 us; speedup vs baseline: 1.0480x; 1.0480x over previous
//
#include <hip/hip_runtime.h>
#include <hip/hip_bf16.h>
#include <stdint.h>

// Problem constants
#define B_  8
#define S_  1024
#define H_  1024
#define NH_ 16
#define HD_ 64
#define M_  (B_*S_)   // 8192 rows of hidden

using bf16x8 = __attribute__((ext_vector_type(8))) __bf16;
using f32x4  = __attribute__((ext_vector_type(4))) float;
using f32x16 = __attribute__((ext_vector_type(16))) float;
typedef int iv2 __attribute__((ext_vector_type(2)));

#define LOG2E 1.4426950408889634f

#if __has_builtin(__builtin_amdgcn_exp2f)
#define EXP2(x) __builtin_amdgcn_exp2f(x)
#else
#define EXP2(x) exp2f(x)
#endif

#define SBAR() asm volatile("s_barrier" ::: "memory")
#define WAITV(n) asm volatile("s_waitcnt vmcnt(" #n ")" ::: "memory")

// async global->LDS, 16B per lane; lds ptr must be wave-uniform (HW adds lane*16)
__device__ __forceinline__ void gload_lds16(const void* g, void* l) {
  __builtin_amdgcn_global_load_lds(
      (const __attribute__((address_space(1))) unsigned int*)g,
      (__attribute__((address_space(3))) unsigned int*)l, 16, 0, 0);
}

// pack two f32 -> one u32 of 2 bf16 (lo in bits 0-15)
__device__ __forceinline__ unsigned pack_bf16(float lo, float hi) {
  unsigned r;
  asm("v_cvt_pk_bf16_f32 %0, %1, %2" : "=v"(r) : "v"(lo), "v"(hi));
  return r;
}

// swap a.hi32lanes <-> b.lo32lanes
__device__ __forceinline__ void swapl32(unsigned& a, unsigned& b) {
#if __has_builtin(__builtin_amdgcn_permlane32_swap)
  iv2 r = __builtin_amdgcn_permlane32_swap((int)a, (int)b, false, false);
  a = (unsigned)r[0];
  b = (unsigned)r[1];
#else
  unsigned axc = (unsigned)__shfl_xor((int)a, 32);
  unsigned bxc = (unsigned)__shfl_xor((int)b, 32);
  int lane = threadIdx.x & 63;
  unsigned an = (lane < 32) ? a : bxc;
  unsigned bn = (lane < 32) ? axc : b;
  a = an; b = bn;
#endif
}

// ---------------------------------------------------------------------------
// fp32 -> bf16 cast, single fused launch: dst is the contiguous Xb|Wq|Wk|Wv
// bf16 region (1,441,792 vec8-chunks); source switches per chunk index.
// ---------------------------------------------------------------------------
#define XCHUNKS 1048576   // M_*H_/8
#define WCHUNKS 131072    // H_*H_/8

__global__ void __launch_bounds__(256) cast_all_bf16_kernel(
    const float* __restrict__ hs,
    const float* __restrict__ w0, const float* __restrict__ w1,
    const float* __restrict__ w2, __bf16* __restrict__ dst) {
  int i = blockIdx.x * blockDim.x + threadIdx.x;  // [0, 1441792)
  const float* s;
  int rem;
  if (i < XCHUNKS) {
    s = hs; rem = i;
  } else {
    int j = i - XCHUNKS;
    int seg = j >> 17;
    rem = j & (WCHUNKS - 1);
    s = (seg == 0) ? w0 : ((seg == 1) ? w1 : w2);
  }
  float4 f0 = ((const float4*)s)[2 * rem];
  float4 f1 = ((const float4*)s)[2 * rem + 1];
  bf16x8 o;
  o[0] = (__bf16)f0.x; o[1] = (__bf16)f0.y; o[2] = (__bf16)f0.z; o[3] = (__bf16)f0.w;
  o[4] = (__bf16)f1.x; o[5] = (__bf16)f1.y; o[6] = (__bf16)f1.z; o[7] = (__bf16)f1.w;
  ((bf16x8*)dst)[i] = o;
}

// ---------------------------------------------------------------------------
// QKV projection GEMM (r8 exact — best measured 88 us, 5-structure plateau):
//   C = X @ W^T + b; BM=256, BN=128, BK=64; 8 waves (4m x 2n), wave 64x64,
//   16x16x32 MFMA (32x32x16 variant regresses: 4-way LDS bank conflict from
//   rows r/r+8/r+16/r+24 sharing a swizzle chunk at 128B row stride — r13).
//   Grid (32, 8, 3) = 768 blocks = 3 blocks/CU x 256 CU = one full round.
//   LDS 48 KB, single-buffered 2-barrier loop, both-sides XOR swizzle.
// Outputs: z=0 -> Q [B,NH,S,HD] * (0.125*log2e) ; z=1 -> K ; z=2 -> V^T
// ---------------------------------------------------------------------------
__global__ void __launch_bounds__(512) qkv_gemm_kernel(
    const __bf16* __restrict__ X,
    const __bf16* __restrict__ Wq, const __bf16* __restrict__ Wk, const __bf16* __restrict__ Wv,
    const float* __restrict__ bq, const float* __restrict__ bk, const float* __restrict__ bv,
    __bf16* __restrict__ Qo, __bf16* __restrict__ Ko, __bf16* __restrict__ Vto) {
  __shared__ __align__(16) char Asm[256 * 128];  // [256 rows][64 k] bf16, swizzled
  __shared__ __align__(16) char Bsm[128 * 128];  // [128 rows][64 k] bf16, swizzled

  const int tid = threadIdx.x;
  const int lane = tid & 63, w = tid >> 6;
  const int l15 = lane & 15, g = lane >> 4;
  const int wm = w >> 1, wn = w & 1;          // 4m x 2n waves
  const int m0 = blockIdx.x * 256;
  const int n0 = blockIdx.y * 128;
  const int z = blockIdx.z;
  const __bf16* W = (z == 0) ? Wq : ((z == 1) ? Wk : Wv);
  const float* bias = (z == 0) ? bq : ((z == 1) ? bk : bv);

  f32x4 acc[4][4] = {};

  for (int kt = 0; kt < H_; kt += 64) {
    __syncthreads();
    // stage A[256][64] (4 rounds) and B[128][64] (2 rounds); pre-swizzled src
#pragma unroll
    for (int is = 0; is < 4; ++is) {
      int q = is * 8192 + tid * 16;            // linear LDS byte this lane fills
      int row = q >> 7;                        // 128B rows
      int inrow = (q & 127) ^ ((row & 7) << 4);
      const char* ga = (const char*)X + (size_t)(m0 + row) * (H_ * 2) + kt * 2 + inrow;
      gload_lds16(ga, Asm + is * 8192 + w * 1024);
    }
#pragma unroll
    for (int is = 0; is < 2; ++is) {
      int q = is * 8192 + tid * 16;
      int row = q >> 7;                        // 0..127
      int inrow = (q & 127) ^ ((row & 7) << 4);
      const char* gb = (const char*)W + (size_t)(n0 + row) * (H_ * 2) + kt * 2 + inrow;
      gload_lds16(gb, Bsm + is * 8192 + w * 1024);
    }
    __syncthreads();
#pragma unroll
    for (int ks = 0; ks < 2; ++ks) {
      bf16x8 a[4], b[4];
#pragma unroll
      for (int i = 0; i < 4; ++i) {
        int row = wm * 64 + i * 16 + l15;
        int chunk = (g + ks * 4) ^ (row & 7);
        a[i] = *reinterpret_cast<const bf16x8*>(Asm + row * 128 + chunk * 16);
      }
#pragma unroll
      for (int j = 0; j < 4; ++j) {
        int row = wn * 64 + j * 16 + l15;
        int chunk = (g + ks * 4) ^ (row & 7);
        b[j] = *reinterpret_cast<const bf16x8*>(Bsm + row * 128 + chunk * 16);
      }
#pragma unroll
      for (int i = 0; i < 4; ++i)
#pragma unroll
        for (int j = 0; j < 4; ++j)
          acc[i][j] = __builtin_amdgcn_mfma_f32_16x16x32_bf16(a[i], b[j], acc[i][j], 0, 0, 0);
    }
  }

  // epilogue: C/D frag row=4g+r, col=l15
#pragma unroll
  for (int i = 0; i < 4; ++i) {
#pragma unroll
    for (int j = 0; j < 4; ++j) {
      int n = n0 + wn * 64 + j * 16 + l15;
      float bs = bias[n];
      int nh = n >> 6, d = n & 63;
#pragma unroll
      for (int r = 0; r < 4; ++r) {
        int m = m0 + wm * 64 + i * 16 + 4 * g + r;
        int bb = m >> 10, s = m & 1023;
        float v = acc[i][j][r] + bs;
        if (z == 0) {
          Qo[(((size_t)bb * NH_ + nh) * S_ + s) * HD_ + d] = (__bf16)(v * (0.125f * LOG2E));
        } else if (z == 1) {
          Ko[(((size_t)bb * NH_ + nh) * S_ + s) * HD_ + d] = (__bf16)v;
        } else {
          Vto[(((size_t)bb * NH_ + nh) * HD_ + d) * S_ + s] = (__bf16)v;
        }
      }
    }
  }
}

// ---------------------------------------------------------------------------
// Flash attention, 8-wave 32x32 + K/V double-buffer + defer-max (r12 exact)
// ---------------------------------------------------------------------------
#define CROW(r, hi) (((r) & 3) + 8 * ((r) >> 2) + 4 * (hi))

__global__ void __launch_bounds__(512) attn_kernel(
    const __bf16* __restrict__ Q,   // [128][1024][64]
    const __bf16* __restrict__ K,   // [128][1024][64]
    const __bf16* __restrict__ Vt,  // [128][64][1024]
    float* __restrict__ Out) {      // [8][1024][1024]
  __shared__ __align__(16) char Ksm[2][8192];
  __shared__ __align__(16) char Vsm[2][8192];
  __shared__ __align__(16) float stat_lds[512];

  const int tid = threadIdx.x, lane = tid & 63, w = tid >> 6;
  const int l31 = lane & 31, hi = lane >> 5;
  const int head = blockIdx.y;
  const int bb = head >> 4, nh = head & 15;
  const int qw = blockIdx.x * 256 + w * 32;

  const char* Qh = (const char*)(Q + (size_t)head * S_ * HD_);
  const char* Kh = (const char*)(K + (size_t)head * S_ * HD_);
  const char* Vh = (const char*)(Vt + (size_t)head * S_ * HD_);

  const int srow = (tid * 16) >> 7;
  const int sinrow = ((tid * 16) & 127) ^ ((srow & 7) << 4);

  bf16x8 qf[4];
#pragma unroll
  for (int slot = 0; slot < 4; ++slot)
    qf[slot] = *reinterpret_cast<const bf16x8*>(
        Qh + (size_t)(qw + l31) * 128 + slot * 32 + hi * 16);

  float m_run = -1e30f, l_run = 0.0f;
  f32x16 accO[2] = {};

  gload_lds16(Kh + (size_t)srow * 128 + sinrow, Ksm[0] + w * 1024);
  gload_lds16(Vh + (size_t)srow * 2048 + sinrow, Vsm[0] + w * 1024);

  for (int t = 0; t < 16; ++t) {
    const int cur = t & 1;
    if (t < 15) {
      const int nxt = cur ^ 1;
      const size_t kvn = (size_t)(t + 1) * 64;
      gload_lds16(Kh + (size_t)(kvn + srow) * 128 + sinrow, Ksm[nxt] + w * 1024);
      gload_lds16(Vh + (size_t)srow * 2048 + kvn * 2 + sinrow, Vsm[nxt] + w * 1024);
      WAITV(2);
    } else {
      WAITV(0);
    }
    SBAR();

    const char* Kc = Ksm[cur];
    const char* Vc = Vsm[cur];

    f32x16 s0 = {}, s1 = {};
    __builtin_amdgcn_s_setprio(1);
#pragma unroll
    for (int slot = 0; slot < 4; ++slot) {
      int c0 = slot * 2 + hi;
      int r0 = l31;
      bf16x8 k0 = *reinterpret_cast<const bf16x8*>(Kc + r0 * 128 + ((c0 ^ (r0 & 7)) << 4));
      int r1 = 32 + l31;
      bf16x8 k1 = *reinterpret_cast<const bf16x8*>(Kc + r1 * 128 + ((c0 ^ (r1 & 7)) << 4));
      s0 = __builtin_amdgcn_mfma_f32_32x32x16_bf16(k0, qf[slot], s0, 0, 0, 0);
      s1 = __builtin_amdgcn_mfma_f32_32x32x16_bf16(k1, qf[slot], s1, 0, 0, 0);
    }
    __builtin_amdgcn_s_setprio(0);

    // ---- online softmax with defer-max (exp2 domain)
    float mx = -1e30f;
#pragma unroll
    for (int r = 0; r < 16; ++r) mx = fmaxf(mx, fmaxf(s0[r], s1[r]));
    mx = fmaxf(mx, __shfl_xor(mx, 32));

    float corr = 1.0f;
    if (!__all(mx - m_run <= 8.0f)) {
      float mnew = fmaxf(m_run, mx);
      corr = EXP2(m_run - mnew);
      m_run = mnew;
      stat_lds[w * 64 + lane] = corr;
      f32x4 c4[4];
#pragma unroll
      for (int rq = 0; rq < 4; ++rq)
        c4[rq] = *reinterpret_cast<const f32x4*>(&stat_lds[w * 64 + rq * 8 + hi * 4]);
#pragma unroll
      for (int r = 0; r < 16; ++r) {
        float cr = c4[r >> 2][r & 3];
        accO[0][r] *= cr;
        accO[1][r] *= cr;
      }
    }

    float sum = 0.0f;
#pragma unroll
    for (int r = 0; r < 16; ++r) {
      float p0 = EXP2(s0[r] - m_run); s0[r] = p0; sum += p0;
      float p1 = EXP2(s1[r] - m_run); s1[r] = p1; sum += p1;
    }
    sum += __shfl_xor(sum, 32);
    l_run = l_run * corr + sum;

    bf16x8 pa[4];
#define BUILD_PA(T, rb)                                                     \
    {                                                                       \
      unsigned x1 = pack_bf16(T[rb + 0], T[rb + 1]);                        \
      unsigned x2 = pack_bf16(T[rb + 2], T[rb + 3]);                        \
      unsigned y1 = pack_bf16(T[rb + 4], T[rb + 5]);                        \
      unsigned y2 = pack_bf16(T[rb + 6], T[rb + 7]);                        \
      swapl32(x1, y1);                                                      \
      swapl32(x2, y2);                                                      \
      union { unsigned u[4]; bf16x8 v; } cvt;                               \
      cvt.u[0] = x1; cvt.u[1] = x2; cvt.u[2] = y1; cvt.u[3] = y2;           \
      pa_out = cvt.v;                                                       \
    }
    {
      bf16x8 pa_out;
      BUILD_PA(s0, 0) pa[0] = pa_out;
      BUILD_PA(s0, 8) pa[1] = pa_out;
      BUILD_PA(s1, 0) pa[2] = pa_out;
      BUILD_PA(s1, 8) pa[3] = pa_out;
    }

    __builtin_amdgcn_s_setprio(1);
#pragma unroll
    for (int ks = 0; ks < 4; ++ks) {
#pragma unroll
      for (int dt = 0; dt < 2; ++dt) {
        int rd = dt * 32 + l31;
        int ck = ks * 2 + hi;
        bf16x8 vb = *reinterpret_cast<const bf16x8*>(Vc + rd * 128 + ((ck ^ (rd & 7)) << 4));
        accO[dt] = __builtin_amdgcn_mfma_f32_32x32x16_bf16(pa[ks], vb, accO[dt], 0, 0, 0);
      }
    }
    __builtin_amdgcn_s_setprio(0);

    SBAR();
  }

  stat_lds[w * 64 + lane] = 1.0f / l_run;
  f32x4 li4[4];
#pragma unroll
  for (int rq = 0; rq < 4; ++rq)
    li4[rq] = *reinterpret_cast<const f32x4*>(&stat_lds[w * 64 + rq * 8 + hi * 4]);

  float* Ob = Out + (size_t)bb * S_ * H_ + (size_t)nh * HD_;
#pragma unroll
  for (int r = 0; r < 16; ++r) {
    int qabs = qw + CROW(r, hi);
    float li = li4[r >> 2][r & 3];
#pragma unroll
    for (int dt = 0; dt < 2; ++dt) {
      int d = dt * 32 + l31;
      Ob[(size_t)qabs * H_ + d] = accO[dt][r] * li;
    }
  }
}

// ---------------------------------------------------------------------------
extern "C" void kernel_launch(void* const* d_in, const int* in_sizes, int n_in,
                              void* d_out, int out_size, void* d_ws, size_t ws_size,
                              hipStream_t stream) {
  const float* hs = (const float*)d_in[0];
  const float* Wq = (const float*)d_in[1];
  const float* bq = (const float*)d_in[2];
  const float* Wk = (const float*)d_in[3];
  const float* bk = (const float*)d_in[4];
  const float* Wv = (const float*)d_in[5];
  const float* bv = (const float*)d_in[6];
  float* out = (float*)d_out;
  char* ws = (char*)d_ws;

  size_t off = 0;
  __bf16* Xb  = (__bf16*)(ws + off); off += (size_t)M_ * H_ * 2;
  __bf16* Wqb = (__bf16*)(ws + off); off += (size_t)H_ * H_ * 2;
  __bf16* Wkb = (__bf16*)(ws + off); off += (size_t)H_ * H_ * 2;
  __bf16* Wvb = (__bf16*)(ws + off); off += (size_t)H_ * H_ * 2;
  __bf16* Qb  = (__bf16*)(ws + off); off += (size_t)M_ * H_ * 2;
  __bf16* Kb  = (__bf16*)(ws + off); off += (size_t)M_ * H_ * 2;
  __bf16* Vtb = (__bf16*)(ws + off); off += (size_t)M_ * H_ * 2;

  // one cast launch covering Xb|Wqb|Wkb|Wvb (contiguous dst)
  cast_all_bf16_kernel<<<(XCHUNKS + 3 * WCHUNKS) / 256, 256, 0, stream>>>(
      hs, Wq, Wk, Wv, Xb);

  qkv_gemm_kernel<<<dim3(M_ / 256, H_ / 128, 3), 512, 0, stream>>>(
      Xb, Wqb, Wkb, Wvb, bq, bk, bv, Qb, Kb, Vtb);

  attn_kernel<<<dim3(S_ / 256, B_ * NH_), 512, 0, stream>>>(Qb, Kb, Vtb, out);
}

// Round 15
// 132.118 us; speedup vs baseline: 1.0626x; 1.0139x over previous
//
#include <hip/hip_runtime.h>
#include <hip/hip_bf16.h>
#include <stdint.h>

// Problem constants
#define B_  8
#define S_  1024
#define H_  1024
#define NH_ 16
#define HD_ 64
#define M_  (B_*S_)   // 8192 rows of hidden

using bf16x8 = __attribute__((ext_vector_type(8))) __bf16;
using f32x4  = __attribute__((ext_vector_type(4))) float;
using f32x16 = __attribute__((ext_vector_type(16))) float;
typedef int iv2 __attribute__((ext_vector_type(2)));

#define LOG2E 1.4426950408889634f

#if __has_builtin(__builtin_amdgcn_exp2f)
#define EXP2(x) __builtin_amdgcn_exp2f(x)
#else
#define EXP2(x) exp2f(x)
#endif

#define SBAR() asm volatile("s_barrier" ::: "memory")
#define WAITV(n) asm volatile("s_waitcnt vmcnt(" #n ")" ::: "memory")

// async global->LDS, 16B per lane; lds ptr must be wave-uniform (HW adds lane*16)
__device__ __forceinline__ void gload_lds16(const void* g, void* l) {
  __builtin_amdgcn_global_load_lds(
      (const __attribute__((address_space(1))) unsigned int*)g,
      (__attribute__((address_space(3))) unsigned int*)l, 16, 0, 0);
}

// pack two f32 -> one u32 of 2 bf16 (lo in bits 0-15)
__device__ __forceinline__ unsigned pack_bf16(float lo, float hi) {
  unsigned r;
  asm("v_cvt_pk_bf16_f32 %0, %1, %2" : "=v"(r) : "v"(lo), "v"(hi));
  return r;
}

// swap a.hi32lanes <-> b.lo32lanes
__device__ __forceinline__ void swapl32(unsigned& a, unsigned& b) {
#if __has_builtin(__builtin_amdgcn_permlane32_swap)
  iv2 r = __builtin_amdgcn_permlane32_swap((int)a, (int)b, false, false);
  a = (unsigned)r[0];
  b = (unsigned)r[1];
#else
  unsigned axc = (unsigned)__shfl_xor((int)a, 32);
  unsigned bxc = (unsigned)__shfl_xor((int)b, 32);
  int lane = threadIdx.x & 63;
  unsigned an = (lane < 32) ? a : bxc;
  unsigned bn = (lane < 32) ? axc : b;
  a = an; b = bn;
#endif
}

// ---------------------------------------------------------------------------
// fp32 -> bf16 cast, single fused launch: dst is the contiguous Xb|Wq|Wk|Wv
// bf16 region (1,441,792 vec8-chunks); source switches per chunk index.
// ---------------------------------------------------------------------------
#define XCHUNKS 1048576   // M_*H_/8
#define WCHUNKS 131072    // H_*H_/8

__global__ void __launch_bounds__(256) cast_all_bf16_kernel(
    const float* __restrict__ hs,
    const float* __restrict__ w0, const float* __restrict__ w1,
    const float* __restrict__ w2, __bf16* __restrict__ dst) {
  int i = blockIdx.x * blockDim.x + threadIdx.x;  // [0, 1441792)
  const float* s;
  int rem;
  if (i < XCHUNKS) {
    s = hs; rem = i;
  } else {
    int j = i - XCHUNKS;
    int seg = j >> 17;
    rem = j & (WCHUNKS - 1);
    s = (seg == 0) ? w0 : ((seg == 1) ? w1 : w2);
  }
  float4 f0 = ((const float4*)s)[2 * rem];
  float4 f1 = ((const float4*)s)[2 * rem + 1];
  bf16x8 o;
  o[0] = (__bf16)f0.x; o[1] = (__bf16)f0.y; o[2] = (__bf16)f0.z; o[3] = (__bf16)f0.w;
  o[4] = (__bf16)f1.x; o[5] = (__bf16)f1.y; o[6] = (__bf16)f1.z; o[7] = (__bf16)f1.w;
  ((bf16x8*)dst)[i] = o;
}

// ---------------------------------------------------------------------------
// QKV projection GEMM (r8 exact — best measured 88 us, 5-structure plateau):
//   C = X @ W^T + b; BM=256, BN=128, BK=64; 8 waves (4m x 2n), wave 64x64,
//   16x16x32 MFMA (32x32x16 variant regresses: r13 measured 6.29M LDS bank
//   conflicts from the 32-row fragment read pattern; this 16-row pattern
//   measures 0).
//   Grid (32, 8, 3) = 768 blocks = 3 blocks/CU x 256 CU = one full round.
//   LDS 48 KB, single-buffered 2-barrier loop, both-sides XOR swizzle.
// Outputs: z=0 -> Q [B,NH,S,HD] * (0.125*log2e) ; z=1 -> K ; z=2 -> V^T
// ---------------------------------------------------------------------------
__global__ void __launch_bounds__(512) qkv_gemm_kernel(
    const __bf16* __restrict__ X,
    const __bf16* __restrict__ Wq, const __bf16* __restrict__ Wk, const __bf16* __restrict__ Wv,
    const float* __restrict__ bq, const float* __restrict__ bk, const float* __restrict__ bv,
    __bf16* __restrict__ Qo, __bf16* __restrict__ Ko, __bf16* __restrict__ Vto) {
  __shared__ __align__(16) char Asm[256 * 128];  // [256 rows][64 k] bf16, swizzled
  __shared__ __align__(16) char Bsm[128 * 128];  // [128 rows][64 k] bf16, swizzled

  const int tid = threadIdx.x;
  const int lane = tid & 63, w = tid >> 6;
  const int l15 = lane & 15, g = lane >> 4;
  const int wm = w >> 1, wn = w & 1;          // 4m x 2n waves
  const int m0 = blockIdx.x * 256;
  const int n0 = blockIdx.y * 128;
  const int z = blockIdx.z;
  const __bf16* W = (z == 0) ? Wq : ((z == 1) ? Wk : Wv);
  const float* bias = (z == 0) ? bq : ((z == 1) ? bk : bv);

  f32x4 acc[4][4] = {};

  for (int kt = 0; kt < H_; kt += 64) {
    __syncthreads();
    // stage A[256][64] (4 rounds) and B[128][64] (2 rounds); pre-swizzled src
#pragma unroll
    for (int is = 0; is < 4; ++is) {
      int q = is * 8192 + tid * 16;            // linear LDS byte this lane fills
      int row = q >> 7;                        // 128B rows
      int inrow = (q & 127) ^ ((row & 7) << 4);
      const char* ga = (const char*)X + (size_t)(m0 + row) * (H_ * 2) + kt * 2 + inrow;
      gload_lds16(ga, Asm + is * 8192 + w * 1024);
    }
#pragma unroll
    for (int is = 0; is < 2; ++is) {
      int q = is * 8192 + tid * 16;
      int row = q >> 7;                        // 0..127
      int inrow = (q & 127) ^ ((row & 7) << 4);
      const char* gb = (const char*)W + (size_t)(n0 + row) * (H_ * 2) + kt * 2 + inrow;
      gload_lds16(gb, Bsm + is * 8192 + w * 1024);
    }
    __syncthreads();
#pragma unroll
    for (int ks = 0; ks < 2; ++ks) {
      bf16x8 a[4], b[4];
#pragma unroll
      for (int i = 0; i < 4; ++i) {
        int row = wm * 64 + i * 16 + l15;
        int chunk = (g + ks * 4) ^ (row & 7);
        a[i] = *reinterpret_cast<const bf16x8*>(Asm + row * 128 + chunk * 16);
      }
#pragma unroll
      for (int j = 0; j < 4; ++j) {
        int row = wn * 64 + j * 16 + l15;
        int chunk = (g + ks * 4) ^ (row & 7);
        b[j] = *reinterpret_cast<const bf16x8*>(Bsm + row * 128 + chunk * 16);
      }
#pragma unroll
      for (int i = 0; i < 4; ++i)
#pragma unroll
        for (int j = 0; j < 4; ++j)
          acc[i][j] = __builtin_amdgcn_mfma_f32_16x16x32_bf16(a[i], b[j], acc[i][j], 0, 0, 0);
    }
  }

  // epilogue: C/D frag row=4g+r, col=l15
#pragma unroll
  for (int i = 0; i < 4; ++i) {
#pragma unroll
    for (int j = 0; j < 4; ++j) {
      int n = n0 + wn * 64 + j * 16 + l15;
      float bs = bias[n];
      int nh = n >> 6, d = n & 63;
#pragma unroll
      for (int r = 0; r < 4; ++r) {
        int m = m0 + wm * 64 + i * 16 + 4 * g + r;
        int bb = m >> 10, s = m & 1023;
        float v = acc[i][j][r] + bs;
        if (z == 0) {
          Qo[(((size_t)bb * NH_ + nh) * S_ + s) * HD_ + d] = (__bf16)(v * (0.125f * LOG2E));
        } else if (z == 1) {
          Ko[(((size_t)bb * NH_ + nh) * S_ + s) * HD_ + d] = (__bf16)v;
        } else {
          Vto[(((size_t)bb * NH_ + nh) * HD_ + d) * S_ + s] = (__bf16)v;
        }
      }
    }
  }
}

// ---------------------------------------------------------------------------
// Flash attention, 8-wave 32x32 + K/V double-buffer + defer-max (r12 logic)
// NEW this round (T1): grid transposed to (head, qtile) so the 4 q-tile
// blocks sharing one head's K/V panel land on the SAME XCD (linear block id
// = head + 128*qtile -> id%8 = head%8) -> K/V panel becomes L2-local.
// Pure index remapping; all verified layout/sync code untouched.
// ---------------------------------------------------------------------------
#define CROW(r, hi) (((r) & 3) + 8 * ((r) >> 2) + 4 * (hi))

__global__ void __launch_bounds__(512) attn_kernel(
    const __bf16* __restrict__ Q,   // [128][1024][64]
    const __bf16* __restrict__ K,   // [128][1024][64]
    const __bf16* __restrict__ Vt,  // [128][64][1024]
    float* __restrict__ Out) {      // [8][1024][1024]
  __shared__ __align__(16) char Ksm[2][8192];
  __shared__ __align__(16) char Vsm[2][8192];
  __shared__ __align__(16) float stat_lds[512];

  const int tid = threadIdx.x, lane = tid & 63, w = tid >> 6;
  const int l31 = lane & 31, hi = lane >> 5;
  const int head = blockIdx.x;                 // T1: head-major
  const int bb = head >> 4, nh = head & 15;
  const int qw = blockIdx.y * 256 + w * 32;    // q-tile from y

  const char* Qh = (const char*)(Q + (size_t)head * S_ * HD_);
  const char* Kh = (const char*)(K + (size_t)head * S_ * HD_);
  const char* Vh = (const char*)(Vt + (size_t)head * S_ * HD_);

  const int srow = (tid * 16) >> 7;
  const int sinrow = ((tid * 16) & 127) ^ ((srow & 7) << 4);

  bf16x8 qf[4];
#pragma unroll
  for (int slot = 0; slot < 4; ++slot)
    qf[slot] = *reinterpret_cast<const bf16x8*>(
        Qh + (size_t)(qw + l31) * 128 + slot * 32 + hi * 16);

  float m_run = -1e30f, l_run = 0.0f;
  f32x16 accO[2] = {};

  gload_lds16(Kh + (size_t)srow * 128 + sinrow, Ksm[0] + w * 1024);
  gload_lds16(Vh + (size_t)srow * 2048 + sinrow, Vsm[0] + w * 1024);

  for (int t = 0; t < 16; ++t) {
    const int cur = t & 1;
    if (t < 15) {
      const int nxt = cur ^ 1;
      const size_t kvn = (size_t)(t + 1) * 64;
      gload_lds16(Kh + (size_t)(kvn + srow) * 128 + sinrow, Ksm[nxt] + w * 1024);
      gload_lds16(Vh + (size_t)srow * 2048 + kvn * 2 + sinrow, Vsm[nxt] + w * 1024);
      WAITV(2);
    } else {
      WAITV(0);
    }
    SBAR();

    const char* Kc = Ksm[cur];
    const char* Vc = Vsm[cur];

    f32x16 s0 = {}, s1 = {};
    __builtin_amdgcn_s_setprio(1);
#pragma unroll
    for (int slot = 0; slot < 4; ++slot) {
      int c0 = slot * 2 + hi;
      int r0 = l31;
      bf16x8 k0 = *reinterpret_cast<const bf16x8*>(Kc + r0 * 128 + ((c0 ^ (r0 & 7)) << 4));
      int r1 = 32 + l31;
      bf16x8 k1 = *reinterpret_cast<const bf16x8*>(Kc + r1 * 128 + ((c0 ^ (r1 & 7)) << 4));
      s0 = __builtin_amdgcn_mfma_f32_32x32x16_bf16(k0, qf[slot], s0, 0, 0, 0);
      s1 = __builtin_amdgcn_mfma_f32_32x32x16_bf16(k1, qf[slot], s1, 0, 0, 0);
    }
    __builtin_amdgcn_s_setprio(0);

    // ---- online softmax with defer-max (exp2 domain)
    float mx = -1e30f;
#pragma unroll
    for (int r = 0; r < 16; ++r) mx = fmaxf(mx, fmaxf(s0[r], s1[r]));
    mx = fmaxf(mx, __shfl_xor(mx, 32));

    float corr = 1.0f;
    if (!__all(mx - m_run <= 8.0f)) {
      float mnew = fmaxf(m_run, mx);
      corr = EXP2(m_run - mnew);
      m_run = mnew;
      stat_lds[w * 64 + lane] = corr;
      f32x4 c4[4];
#pragma unroll
      for (int rq = 0; rq < 4; ++rq)
        c4[rq] = *reinterpret_cast<const f32x4*>(&stat_lds[w * 64 + rq * 8 + hi * 4]);
#pragma unroll
      for (int r = 0; r < 16; ++r) {
        float cr = c4[r >> 2][r & 3];
        accO[0][r] *= cr;
        accO[1][r] *= cr;
      }
    }

    float sum = 0.0f;
#pragma unroll
    for (int r = 0; r < 16; ++r) {
      float p0 = EXP2(s0[r] - m_run); s0[r] = p0; sum += p0;
      float p1 = EXP2(s1[r] - m_run); s1[r] = p1; sum += p1;
    }
    sum += __shfl_xor(sum, 32);
    l_run = l_run * corr + sum;

    bf16x8 pa[4];
#define BUILD_PA(T, rb)                                                     \
    {                                                                       \
      unsigned x1 = pack_bf16(T[rb + 0], T[rb + 1]);                        \
      unsigned x2 = pack_bf16(T[rb + 2], T[rb + 3]);                        \
      unsigned y1 = pack_bf16(T[rb + 4], T[rb + 5]);                        \
      unsigned y2 = pack_bf16(T[rb + 6], T[rb + 7]);                        \
      swapl32(x1, y1);                                                      \
      swapl32(x2, y2);                                                      \
      union { unsigned u[4]; bf16x8 v; } cvt;                               \
      cvt.u[0] = x1; cvt.u[1] = x2; cvt.u[2] = y1; cvt.u[3] = y2;           \
      pa_out = cvt.v;                                                       \
    }
    {
      bf16x8 pa_out;
      BUILD_PA(s0, 0) pa[0] = pa_out;
      BUILD_PA(s0, 8) pa[1] = pa_out;
      BUILD_PA(s1, 0) pa[2] = pa_out;
      BUILD_PA(s1, 8) pa[3] = pa_out;
    }

    __builtin_amdgcn_s_setprio(1);
#pragma unroll
    for (int ks = 0; ks < 4; ++ks) {
#pragma unroll
      for (int dt = 0; dt < 2; ++dt) {
        int rd = dt * 32 + l31;
        int ck = ks * 2 + hi;
        bf16x8 vb = *reinterpret_cast<const bf16x8*>(Vc + rd * 128 + ((ck ^ (rd & 7)) << 4));
        accO[dt] = __builtin_amdgcn_mfma_f32_32x32x16_bf16(pa[ks], vb, accO[dt], 0, 0, 0);
      }
    }
    __builtin_amdgcn_s_setprio(0);

    SBAR();
  }

  stat_lds[w * 64 + lane] = 1.0f / l_run;
  f32x4 li4[4];
#pragma unroll
  for (int rq = 0; rq < 4; ++rq)
    li4[rq] = *reinterpret_cast<const f32x4*>(&stat_lds[w * 64 + rq * 8 + hi * 4]);

  float* Ob = Out + (size_t)bb * S_ * H_ + (size_t)nh * HD_;
#pragma unroll
  for (int r = 0; r < 16; ++r) {
    int qabs = qw + CROW(r, hi);
    float li = li4[r >> 2][r & 3];
#pragma unroll
    for (int dt = 0; dt < 2; ++dt) {
      int d = dt * 32 + l31;
      Ob[(size_t)qabs * H_ + d] = accO[dt][r] * li;
    }
  }
}

// ---------------------------------------------------------------------------
extern "C" void kernel_launch(void* const* d_in, const int* in_sizes, int n_in,
                              void* d_out, int out_size, void* d_ws, size_t ws_size,
                              hipStream_t stream) {
  const float* hs = (const float*)d_in[0];
  const float* Wq = (const float*)d_in[1];
  const float* bq = (const float*)d_in[2];
  const float* Wk = (const float*)d_in[3];
  const float* bk = (const float*)d_in[4];
  const float* Wv = (const float*)d_in[5];
  const float* bv = (const float*)d_in[6];
  float* out = (float*)d_out;
  char* ws = (char*)d_ws;

  size_t off = 0;
  __bf16* Xb  = (__bf16*)(ws + off); off += (size_t)M_ * H_ * 2;
  __bf16* Wqb = (__bf16*)(ws + off); off += (size_t)H_ * H_ * 2;
  __bf16* Wkb = (__bf16*)(ws + off); off += (size_t)H_ * H_ * 2;
  __bf16* Wvb = (__bf16*)(ws + off); off += (size_t)H_ * H_ * 2;
  __bf16* Qb  = (__bf16*)(ws + off); off += (size_t)M_ * H_ * 2;
  __bf16* Kb  = (__bf16*)(ws + off); off += (size_t)M_ * H_ * 2;
  __bf16* Vtb = (__bf16*)(ws + off); off += (size_t)M_ * H_ * 2;

  // one cast launch covering Xb|Wqb|Wkb|Wvb (contiguous dst)
  cast_all_bf16_kernel<<<(XCHUNKS + 3 * WCHUNKS) / 256, 256, 0, stream>>>(
      hs, Wq, Wk, Wv, Xb);

  qkv_gemm_kernel<<<dim3(M_ / 256, H_ / 128, 3), 512, 0, stream>>>(
      Xb, Wqb, Wkb, Wvb, bq, bk, bv, Qb, Kb, Vtb);

  // T1: head-major grid -> same-head q-tile blocks share an XCD (L2-local K/V)
  attn_kernel<<<dim3(B_ * NH_, S_ / 256), 512, 0, stream>>>(Qb, Kb, Vtb, out);
}